// Round 7
// baseline (33.008 us; speedup 1.0000x reference)
//
#include <hip/hip_runtime.h>

#define NROWS 4096
#define DIM 128
#define PCLS 1024
#define NPAIR 6144
#define MARGIN 1.0f
#define EPS 1e-6f
#define LOG2E 1.4426950408889634f
#define NSPLIT 32

typedef __attribute__((ext_vector_type(8))) short bf16x8;
typedef __attribute__((ext_vector_type(4))) float f32x4;

union FragU { uint4 u; bf16x8 v; ushort us[8]; };

__device__ __forceinline__ unsigned short f2bf(float f) {
    unsigned int b = __float_as_uint(f);
    b = (b + 0x7FFFu + ((b >> 16) & 1u)) >> 16;
    return (unsigned short)b;
}
__device__ __forceinline__ float bf2f(unsigned short u) {
    return __uint_as_float((unsigned int)u << 16);
}

// Upper-triangular 128x128 Gram tiles straight from f32 x (fused norms +
// bf16 conversion; no prep kernel). Each e=exp(1-d) feeds BOTH the row sum
// (slot=cb) and, off-diag, the col sum (slot=rb).
// Grid: 528 blocks = 32*33/2 upper-tri pairs, 512 thr (8 waves x 16 rows).
__launch_bounds__(512, 4)
__global__ void main_kernel(const float* __restrict__ x,
                            unsigned short* __restrict__ partial,
                            float* __restrict__ posD) {
    __shared__ __align__(16) unsigned short lds[128 * DIM]; // 32 KB bf16 B-panel
    __shared__ float colW[8 * 128];                          // 4 KB col-sum xchg
    __shared__ float normBuf[256];                           // 128 row + 128 col norms
    const int t = threadIdx.x;
    const int w = t >> 6;
    const int l = t & 63;
    const int lg = l >> 4;                 // k-group (0..3)
    const int lr = l & 15;                 // frag row/col index

    // triangular decode: u -> (rb, cb), rb <= cb
    int u = blockIdx.x;
    int rb = (int)((65.0f - sqrtf(4225.0f - 8.0f * (float)u)) * 0.5f);
    while (rb > 0 && rb * (65 - rb) / 2 > u) --rb;
    while ((rb + 1) * (64 - rb) / 2 <= u) ++rb;
    const int cb = rb + (u - rb * (65 - rb) / 2);
    const bool offd = (cb != rb);

    const int rbase = rb * 128 + w * 16;   // this wave's 16 rows
    const int cbase = cb * 128;

    // ---- norm pass: 256 norms (128 A-rows, 128 B-cols), 2 half-tasks each
    {
        int idx = t >> 1, half = t & 1;
        int grow = (idx < 128) ? (rb * 128 + idx) : (cbase + idx - 128);
        const float4* p = reinterpret_cast<const float4*>(
            x + (size_t)grow * DIM + half * 64);
        float s = 0.f;
        #pragma unroll
        for (int q = 0; q < 16; ++q) {
            float4 v = p[q];
            s = fmaf(v.x, v.x, s); s = fmaf(v.y, v.y, s);
            s = fmaf(v.z, v.z, s); s = fmaf(v.w, v.w, s);
        }
        s += __shfl_xor(s, 1, 64);
        if (!half) normBuf[idx] = s;
    }

    // ---- A fragments (16 rows x 128 k): f32 load + in-register bf16 convert
    FragU afr[4];
    const float* arow = x + (size_t)(rbase + lr) * DIM;
    #pragma unroll
    for (int s = 0; s < 4; ++s) {
        const float4* ap = reinterpret_cast<const float4*>(arow + s * 32 + lg * 8);
        float4 a0 = ap[0], a1 = ap[1];
        afr[s].us[0] = f2bf(a0.x); afr[s].us[1] = f2bf(a0.y);
        afr[s].us[2] = f2bf(a0.z); afr[s].us[3] = f2bf(a0.w);
        afr[s].us[4] = f2bf(a1.x); afr[s].us[5] = f2bf(a1.y);
        afr[s].us[6] = f2bf(a1.z); afr[s].us[7] = f2bf(a1.w);
    }

    // ---- stage B-panel (128 cols x 128 k) f32 -> bf16, XOR-swizzled layout
    #pragma unroll
    for (int q = 0; q < 8; ++q) {
        int lin = q * 4096 + t * 8;        // byte offset in bf16 panel
        int col = lin >> 8;
        int inner = lin & 255;             // multiple of 8
        float4 v = *reinterpret_cast<const float4*>(
            x + (size_t)(cbase + col) * DIM + (inner >> 1));
        ushort4 h = { f2bf(v.x), f2bf(v.y), f2bf(v.z), f2bf(v.w) };
        *reinterpret_cast<ushort4*>(
            (char*)lds + col * 256 + (inner ^ ((col & 7) << 4))) = h;
    }

    __syncthreads();

    // per-lane norms from LDS
    float njv[8];
    #pragma unroll
    for (int tile = 0; tile < 8; ++tile)
        njv[tile] = normBuf[128 + tile * 16 + lr];
    float ni[4];
    #pragma unroll
    for (int rr = 0; rr < 4; ++rr)
        ni[rr] = normBuf[w * 16 + lg * 4 + rr] + EPS;   // fold +EPS

    float accS[4] = {0.f, 0.f, 0.f, 0.f};
    float colA[8];

    #pragma unroll
    for (int tile = 0; tile < 8; ++tile) {
        const int lcol = tile * 16 + lr;
        const float nj = njv[tile];
        const char* bbase = (const char*)lds + lcol * 256;
        const int xr = (lcol & 7) << 4;
        f32x4 acc = {0.f, 0.f, 0.f, 0.f};
        #pragma unroll
        for (int s = 0; s < 4; ++s) {
            FragU bu;
            int inner = s * 64 + lg * 16;
            bu.u = *reinterpret_cast<const uint4*>(bbase + (inner ^ xr));
            acc = __builtin_amdgcn_mfma_f32_16x16x32_bf16(afr[s].v, bu.v, acc, 0, 0, 0);
        }
        if (offd) {
            float es = 0.f;
            #pragma unroll
            for (int rr = 0; rr < 4; ++rr) {
                float nn = ni[rr] + nj;
                float d2 = fmaf(-2.0f, acc[rr], nn);
                float d = __builtin_amdgcn_sqrtf(fmaxf(d2, EPS));
                float e = __builtin_amdgcn_exp2f(fmaf(d, -LOG2E, LOG2E));
                accS[rr] += e;
                es += e;
            }
            colA[tile] = es;
        } else if (tile != w) {
            #pragma unroll
            for (int rr = 0; rr < 4; ++rr) {
                float nn = ni[rr] + nj;
                float d2 = fmaf(-2.0f, acc[rr], nn);
                float d = __builtin_amdgcn_sqrtf(fmaxf(d2, EPS));
                accS[rr] += __builtin_amdgcn_exp2f(fmaf(d, -LOG2E, LOG2E));
            }
        } else {
            // diagonal 16x16 tile: same-class masking + positive-pair extraction
            #pragma unroll
            for (int rr = 0; rr < 4; ++rr) {
                int a = lg * 4 + rr;               // local row 0..15
                int b = lr;                        // local col 0..15
                float nn = ni[rr] + nj;
                float d2 = fmaf(-2.0f, acc[rr], nn);
                float d = __builtin_amdgcn_sqrtf(fmaxf(d2, EPS));
                float e = __builtin_amdgcn_exp2f(fmaf(d, -LOG2E, LOG2E));
                bool same = (a >> 2) == (b >> 2);
                accS[rr] += same ? 0.f : e;
                if (same && a < b) {
                    int i = a & 3, j = b & 3;
                    int idx = i * (7 - i) / 2 + (j - i - 1);
                    int cls = (rbase + a) >> 2;
                    posD[cls * 6 + idx] = d;
                }
            }
        }
    }

    // row sums: reduce over the 16 col-lanes
    #pragma unroll
    for (int rr = 0; rr < 4; ++rr) {
        #pragma unroll
        for (int m = 1; m < 16; m <<= 1) accS[rr] += __shfl_xor(accS[rr], m, 64);
    }
    if (lr == 0) {
        #pragma unroll
        for (int rr = 0; rr < 4; ++rr)
            partial[cb * NROWS + rbase + lg * 4 + rr] = f2bf(accS[rr]);
    }

    // col sums (off-diag only): reduce over lg within wave, then across waves
    if (offd) {
        #pragma unroll
        for (int tile = 0; tile < 8; ++tile) {
            colA[tile] += __shfl_xor(colA[tile], 16, 64);
            colA[tile] += __shfl_xor(colA[tile], 32, 64);
        }
        if (l < 16) {
            #pragma unroll
            for (int tile = 0; tile < 8; ++tile)
                colW[w * 128 + tile * 16 + l] = colA[tile];
        }
        __syncthreads();
        if (t < 128) {
            float s = 0.f;
            #pragma unroll
            for (int ww = 0; ww < 8; ++ww) s += colW[ww * 128 + t];
            partial[rb * NROWS + cbase + t] = f2bf(s);
        }
    }
}

// single block: S = sum of 32 bf16 split panels, J per pair, relu^2, mean
__global__ void tail_kernel(const unsigned short* __restrict__ partial,
                            const float* __restrict__ posD,
                            float* __restrict__ out) {
    const int c = threadIdx.x;    // class 0..1023
    float S[4] = {0.f, 0.f, 0.f, 0.f};
    #pragma unroll
    for (int sp = 0; sp < NSPLIT; ++sp) {
        ushort4 v = *reinterpret_cast<const ushort4*>(partial + sp * NROWS + 4 * c);
        S[0] += bf2f(v.x); S[1] += bf2f(v.y); S[2] += bf2f(v.z); S[3] += bf2f(v.w);
    }
    const int II[6] = {0, 0, 0, 1, 1, 2};
    const int JJ[6] = {1, 2, 3, 2, 3, 3};
    float acc = 0.f;
    #pragma unroll
    for (int p = 0; p < 6; ++p) {
        float d = posD[c * 6 + p];
        float J = __logf(S[II[p]] + S[JJ[p]]) + d;
        float r = fmaxf(J, 0.f);
        acc += r * r;
    }
    // block reduce 1024 -> 1
    #pragma unroll
    for (int m = 1; m < 64; m <<= 1) acc += __shfl_xor(acc, m, 64);
    __shared__ float red[16];
    if ((c & 63) == 0) red[c >> 6] = acc;
    __syncthreads();
    if (c < 64) {
        float v = (c < 16) ? red[c] : 0.f;
        #pragma unroll
        for (int m = 1; m < 16; m <<= 1) v += __shfl_xor(v, m, 64);
        if (c == 0) out[0] = v * (1.0f / (2.0f * (float)NPAIR));
    }
}

extern "C" void kernel_launch(void* const* d_in, const int* in_sizes, int n_in,
                              void* d_out, int out_size, void* d_ws, size_t ws_size,
                              hipStream_t stream) {
    const float* x = (const float*)d_in[0];
    char* ws = (char*)d_ws;
    unsigned short* partial = (unsigned short*)ws;            // 32*4096 bf16 = 256 KB
    float* posD = (float*)(ws + 262144);                      // 24 KB
    float* out = (float*)d_out;

    hipLaunchKernelGGL(main_kernel, dim3(528), dim3(512), 0, stream, x, partial, posD);
    hipLaunchKernelGGL(tail_kernel, dim3(1), dim3(1024), 0, stream, partial, posD, out);
}

// Round 8
// 26.102 us; speedup vs baseline: 1.2646x; 1.2646x over previous
//
#include <hip/hip_runtime.h>

#define NROWS 4096
#define DIM 128
#define PCLS 1024
#define NPAIR 6144
#define MARGIN 1.0f
#define EPS 1e-6f
#define LOG2E 1.4426950408889634f
#define NSPLIT 32

typedef __attribute__((ext_vector_type(8))) short bf16x8;
typedef __attribute__((ext_vector_type(4))) float f32x4;

union FragU { uint4 u; bf16x8 v; };

__device__ __forceinline__ unsigned short f2bf(float f) {
    unsigned int b = __float_as_uint(f);
    b = (b + 0x7FFFu + ((b >> 16) & 1u)) >> 16;
    return (unsigned short)b;
}
__device__ __forceinline__ float bf2f(unsigned short u) {
    return __uint_as_float((unsigned int)u << 16);
}

// one wave per row: norms (f32) + bf16 conversion
__global__ void prep_kernel(const float* __restrict__ x,
                            unsigned short* __restrict__ xbf,
                            float* __restrict__ norms) {
    int row = blockIdx.x * 4 + (threadIdx.x >> 6);
    int l = threadIdx.x & 63;
    float2 v = *reinterpret_cast<const float2*>(x + row * DIM + 2 * l);
    unsigned int packed = (unsigned int)f2bf(v.x) | ((unsigned int)f2bf(v.y) << 16);
    *reinterpret_cast<unsigned int*>(xbf + row * DIM + 2 * l) = packed;
    float s = v.x * v.x + v.y * v.y;
    #pragma unroll
    for (int m = 1; m < 64; m <<= 1) s += __shfl_xor(s, m, 64);
    if (l == 0) norms[row] = s;
}

// Upper-triangular 128x128 Gram tiles; each e=exp(1-d) feeds BOTH the row
// sum (slot=cb) and, for off-diag blocks, the col sum (slot=rb).
// Register-double-buffered B-fragment pipeline hides ds_read latency.
// Grid: 528 blocks = 32*33/2 upper-tri pairs, 512 thr (8 waves x 16 rows).
__launch_bounds__(512, 4)
__global__ void main_kernel(const unsigned short* __restrict__ xbf,
                            const float* __restrict__ norms,
                            unsigned short* __restrict__ partial,
                            float* __restrict__ posD) {
    __shared__ __align__(16) unsigned short lds[128 * DIM]; // 32 KB B-panel
    __shared__ float colW[8 * 128];                          // 4 KB col-sum xchg
    const int t = threadIdx.x;
    const int w = t >> 6;
    const int l = t & 63;
    const int lg = l >> 4;                 // k-group (0..3)
    const int lr = l & 15;                 // frag row/col index

    // triangular decode: u -> (rb, cb), rb <= cb
    int u = blockIdx.x;
    int rb = (int)((65.0f - sqrtf(4225.0f - 8.0f * (float)u)) * 0.5f);
    while (rb > 0 && rb * (65 - rb) / 2 > u) --rb;
    while ((rb + 1) * (64 - rb) / 2 <= u) ++rb;
    const int cb = rb + (u - rb * (65 - rb) / 2);
    const bool offd = (cb != rb);

    const int rbase = rb * 128 + w * 16;   // this wave's 16 rows
    const int cbase = cb * 128;

    // A fragments (16 rows x 128 k) in registers, straight from global
    FragU afr[4];
    const char* abase = (const char*)xbf + (size_t)(rbase + lr) * 256 + lg * 16;
    #pragma unroll
    for (int s = 0; s < 4; ++s)
        afr[s].u = *reinterpret_cast<const uint4*>(abase + s * 64);

    // prefetch column norms (latency hidden by staging + barrier)
    float njv[8];
    #pragma unroll
    for (int tile = 0; tile < 8; ++tile)
        njv[tile] = norms[cbase + tile * 16 + lr];

    // row norms with +EPS folded: sqrt(max(d2,0)+eps) == sqrt(max(d2+eps,eps))
    float ni[4];
    #pragma unroll
    for (int rr = 0; rr < 4; ++rr)
        ni[rr] = norms[rbase + lg * 4 + rr] + EPS;

    // stage 128 cols x 128 k (bf16) with XOR-swizzled LDS layout
    #pragma unroll
    for (int it = 0; it < 4; ++it) {
        int lin = it * 8192 + t * 16;
        int col = lin >> 8;
        int inner = lin & 255;
        uint4 v = *reinterpret_cast<const uint4*>(
            (const char*)xbf + (size_t)(cbase + col) * 256 + inner);
        *reinterpret_cast<uint4*>(
            (char*)lds + col * 256 + (inner ^ ((col & 7) << 4))) = v;
    }

    __syncthreads();

    float accS[4] = {0.f, 0.f, 0.f, 0.f};
    float colA[8];

    // register double-buffered B fragments: load tile t+1 while computing t
    FragU bu0[4], bu1[4];
    {
        const char* bbase = (const char*)lds + lr * 256;       // tile 0
        const int xr = (lr & 7) << 4;
        #pragma unroll
        for (int s = 0; s < 4; ++s)
            bu0[s].u = *reinterpret_cast<const uint4*>(bbase + ((s * 64 + lg * 16) ^ xr));
    }

    #pragma unroll
    for (int tile = 0; tile < 8; ++tile) {
        FragU* cur = (tile & 1) ? bu1 : bu0;
        FragU* nxt = (tile & 1) ? bu0 : bu1;
        if (tile < 7) {
            const int nlcol = (tile + 1) * 16 + lr;
            const char* nbbase = (const char*)lds + nlcol * 256;
            const int nxr = (nlcol & 7) << 4;
            #pragma unroll
            for (int s = 0; s < 4; ++s)
                nxt[s].u = *reinterpret_cast<const uint4*>(nbbase + ((s * 64 + lg * 16) ^ nxr));
        }
        const float nj = njv[tile];
        f32x4 acc = {0.f, 0.f, 0.f, 0.f};
        #pragma unroll
        for (int s = 0; s < 4; ++s)
            acc = __builtin_amdgcn_mfma_f32_16x16x32_bf16(afr[s].v, cur[s].v, acc, 0, 0, 0);

        if (offd) {
            float es = 0.f;
            #pragma unroll
            for (int rr = 0; rr < 4; ++rr) {
                float nn = ni[rr] + nj;
                float d2 = fmaf(-2.0f, acc[rr], nn);
                float d = __builtin_amdgcn_sqrtf(fmaxf(d2, EPS));
                float e = __builtin_amdgcn_exp2f(fmaf(d, -LOG2E, LOG2E));
                accS[rr] += e;
                es += e;
            }
            colA[tile] = es;
        } else if (tile != w) {
            #pragma unroll
            for (int rr = 0; rr < 4; ++rr) {
                float nn = ni[rr] + nj;
                float d2 = fmaf(-2.0f, acc[rr], nn);
                float d = __builtin_amdgcn_sqrtf(fmaxf(d2, EPS));
                accS[rr] += __builtin_amdgcn_exp2f(fmaf(d, -LOG2E, LOG2E));
            }
        } else {
            // diagonal 16x16 tile: same-class masking + positive-pair extraction
            #pragma unroll
            for (int rr = 0; rr < 4; ++rr) {
                int a = lg * 4 + rr;               // local row 0..15
                int b = lr;                        // local col 0..15
                float nn = ni[rr] + nj;
                float d2 = fmaf(-2.0f, acc[rr], nn);
                float d = __builtin_amdgcn_sqrtf(fmaxf(d2, EPS));
                float e = __builtin_amdgcn_exp2f(fmaf(d, -LOG2E, LOG2E));
                bool same = (a >> 2) == (b >> 2);
                accS[rr] += same ? 0.f : e;
                if (same && a < b) {
                    int i = a & 3, j = b & 3;
                    int idx = i * (7 - i) / 2 + (j - i - 1);
                    int cls = (rbase + a) >> 2;
                    posD[cls * 6 + idx] = d;
                }
            }
        }
    }

    // row sums: reduce over the 16 col-lanes
    #pragma unroll
    for (int rr = 0; rr < 4; ++rr) {
        #pragma unroll
        for (int m = 1; m < 16; m <<= 1) accS[rr] += __shfl_xor(accS[rr], m, 64);
    }
    if (lr == 0) {
        #pragma unroll
        for (int rr = 0; rr < 4; ++rr)
            partial[cb * NROWS + rbase + lg * 4 + rr] = f2bf(accS[rr]);
    }

    // col sums (off-diag only): reduce over lg within wave, then across waves
    if (offd) {
        #pragma unroll
        for (int tile = 0; tile < 8; ++tile) {
            colA[tile] += __shfl_xor(colA[tile], 16, 64);
            colA[tile] += __shfl_xor(colA[tile], 32, 64);
        }
        if (l < 16) {
            #pragma unroll
            for (int tile = 0; tile < 8; ++tile)
                colW[w * 128 + tile * 16 + l] = colA[tile];
        }
        __syncthreads();
        if (t < 128) {
            float s = 0.f;
            #pragma unroll
            for (int ww = 0; ww < 8; ++ww) s += colW[ww * 128 + t];
            partial[rb * NROWS + cbase + t] = f2bf(s);
        }
    }
}

// single block: S = sum of 32 bf16 split panels, J per pair, relu^2, mean
__global__ void tail_kernel(const unsigned short* __restrict__ partial,
                            const float* __restrict__ posD,
                            float* __restrict__ out) {
    const int c = threadIdx.x;    // class 0..1023
    float S[4] = {0.f, 0.f, 0.f, 0.f};
    #pragma unroll
    for (int sp = 0; sp < NSPLIT; ++sp) {
        ushort4 v = *reinterpret_cast<const ushort4*>(partial + sp * NROWS + 4 * c);
        S[0] += bf2f(v.x); S[1] += bf2f(v.y); S[2] += bf2f(v.z); S[3] += bf2f(v.w);
    }
    const int II[6] = {0, 0, 0, 1, 1, 2};
    const int JJ[6] = {1, 2, 3, 2, 3, 3};
    float acc = 0.f;
    #pragma unroll
    for (int p = 0; p < 6; ++p) {
        float d = posD[c * 6 + p];
        float J = __logf(S[II[p]] + S[JJ[p]]) + d;
        float r = fmaxf(J, 0.f);
        acc += r * r;
    }
    // block reduce 1024 -> 1
    #pragma unroll
    for (int m = 1; m < 64; m <<= 1) acc += __shfl_xor(acc, m, 64);
    __shared__ float red[16];
    if ((c & 63) == 0) red[c >> 6] = acc;
    __syncthreads();
    if (c < 64) {
        float v = (c < 16) ? red[c] : 0.f;
        #pragma unroll
        for (int m = 1; m < 16; m <<= 1) v += __shfl_xor(v, m, 64);
        if (c == 0) out[0] = v * (1.0f / (2.0f * (float)NPAIR));
    }
}

extern "C" void kernel_launch(void* const* d_in, const int* in_sizes, int n_in,
                              void* d_out, int out_size, void* d_ws, size_t ws_size,
                              hipStream_t stream) {
    const float* x = (const float*)d_in[0];
    char* ws = (char*)d_ws;
    unsigned short* xbf = (unsigned short*)ws;                        // 1 MB
    float* norms = (float*)(ws + 1048576);                            // 16 KB
    unsigned short* partial = (unsigned short*)(ws + 1048576 + 16384);// 32*4096 bf16 = 256 KB
    float* posD = (float*)(ws + 1048576 + 16384 + 262144);            // 24 KB
    float* out = (float*)d_out;

    hipLaunchKernelGGL(prep_kernel, dim3(NROWS / 4), dim3(256), 0, stream, x, xbf, norms);
    hipLaunchKernelGGL(main_kernel, dim3(528), dim3(512), 0, stream, xbf, norms, partial, posD);
    hipLaunchKernelGGL(tail_kernel, dim3(1), dim3(1024), 0, stream, partial, posD, out);
}

// Round 9
// 23.834 us; speedup vs baseline: 1.3849x; 1.0952x over previous
//
#include <hip/hip_runtime.h>

#define NROWS 4096
#define DIM 128
#define PCLS 1024
#define NPAIR 6144
#define MARGIN 1.0f
#define EPS 1e-6f
#define LOG2E 1.4426950408889634f
#define NSPLIT 16

typedef __attribute__((ext_vector_type(8))) short bf16x8;
typedef __attribute__((ext_vector_type(4))) float f32x4;

union FragU { uint4 u; bf16x8 v; };

__device__ __forceinline__ unsigned short f2bf(float f) {
    unsigned int b = __float_as_uint(f);
    b = (b + 0x7FFFu + ((b >> 16) & 1u)) >> 16;
    return (unsigned short)b;
}
__device__ __forceinline__ float bf2f(unsigned short u) {
    return __uint_as_float((unsigned int)u << 16);
}

// one wave per row: norms (f32) + bf16 conversion
__global__ void prep_kernel(const float* __restrict__ x,
                            unsigned short* __restrict__ xbf,
                            float* __restrict__ norms) {
    int row = blockIdx.x * 4 + (threadIdx.x >> 6);
    int l = threadIdx.x & 63;
    float2 v = *reinterpret_cast<const float2*>(x + row * DIM + 2 * l);
    unsigned int packed = (unsigned int)f2bf(v.x) | ((unsigned int)f2bf(v.y) << 16);
    *reinterpret_cast<unsigned int*>(xbf + row * DIM + 2 * l) = packed;
    float s = v.x * v.x + v.y * v.y;
    #pragma unroll
    for (int m = 1; m < 64; m <<= 1) s += __shfl_xor(s, m, 64);
    if (l == 0) norms[row] = s;
}

// Gram tiles via bf16 MFMA + fused exp epilogue + positive-pair extraction.
// grid: 32 row-blocks (128 rows) x 16 col-splits (256 cols) = 512 blocks, 512 thr.
// (R4 structure — best measured config; 2.0 blocks/CU, no straggler round.)
__launch_bounds__(512, 4)
__global__ void main_kernel(const unsigned short* __restrict__ xbf,
                            const float* __restrict__ norms,
                            unsigned short* __restrict__ partial,
                            float* __restrict__ posD) {
    __shared__ __align__(16) unsigned short lds[256 * DIM]; // 64 KB, 256 staged cols
    const int t = threadIdx.x;
    const int w = t >> 6;
    const int l = t & 63;
    const int rb = blockIdx.x >> 4;
    const int cs = blockIdx.x & 15;
    const int rbase = rb * 128 + w * 16;   // this wave's 16 rows
    const int cbase = cs * 256;
    const int lg = l >> 4;                 // k-group (0..3)
    const int lr = l & 15;                 // frag row/col index

    // A fragments (16 rows x 128 k) in registers, straight from global
    FragU afr[4];
    const char* abase = (const char*)xbf + (size_t)(rbase + lr) * 256 + lg * 16;
    #pragma unroll
    for (int s = 0; s < 4; ++s)
        afr[s].u = *reinterpret_cast<const uint4*>(abase + s * 64);

    // prefetch ALL column norms (latency hidden by staging + barrier)
    float njv[16];
    #pragma unroll
    for (int tile = 0; tile < 16; ++tile)
        njv[tile] = norms[cbase + tile * 16 + lr];

    // row norms with +EPS folded: sqrt(max(d2,0)+eps) == sqrt(max(d2+eps,eps))
    float ni[4];
    #pragma unroll
    for (int rr = 0; rr < 4; ++rr)
        ni[rr] = norms[rbase + lg * 4 + rr] + EPS;

    // stage 256 cols x 128 k (bf16) with XOR-swizzled LDS layout
    #pragma unroll
    for (int it = 0; it < 8; ++it) {
        int lin = it * 8192 + t * 16;
        int col = lin >> 8;
        int inner = lin & 255;
        uint4 v = *reinterpret_cast<const uint4*>(
            (const char*)xbf + (size_t)(cbase + col) * 256 + inner);
        *reinterpret_cast<uint4*>(
            (char*)lds + col * 256 + (inner ^ ((col & 7) << 4))) = v;
    }

    __syncthreads();

    float accS[4] = {0.f, 0.f, 0.f, 0.f};

    #pragma unroll
    for (int tile = 0; tile < 16; ++tile) {
        const int lcol = tile * 16 + lr;
        const float nj = njv[tile];
        const char* bbase = (const char*)lds + lcol * 256;
        const int xr = (lcol & 7) << 4;
        f32x4 acc = {0.f, 0.f, 0.f, 0.f};
        #pragma unroll
        for (int s = 0; s < 4; ++s) {
            FragU bu;
            int inner = s * 64 + lg * 16;
            bu.u = *reinterpret_cast<const uint4*>(bbase + (inner ^ xr));
            acc = __builtin_amdgcn_mfma_f32_16x16x32_bf16(afr[s].v, bu.v, acc, 0, 0, 0);
        }
        const bool diag = (cbase + tile * 16) == rbase;  // wave-uniform
        if (!diag) {
            #pragma unroll
            for (int rr = 0; rr < 4; ++rr) {
                float nn = ni[rr] + nj;
                float d2 = fmaf(-2.0f, acc[rr], nn);
                float d = __builtin_amdgcn_sqrtf(fmaxf(d2, EPS));
                accS[rr] += __builtin_amdgcn_exp2f(fmaf(d, -LOG2E, LOG2E));
            }
        } else {
            // diagonal 16x16 tile: same-class masking + positive-pair extraction
            #pragma unroll
            for (int rr = 0; rr < 4; ++rr) {
                int a = lg * 4 + rr;               // local row 0..15
                int b = lr;                        // local col 0..15
                float nn = ni[rr] + nj;
                float d2 = fmaf(-2.0f, acc[rr], nn);
                float d = __builtin_amdgcn_sqrtf(fmaxf(d2, EPS));
                float e = __builtin_amdgcn_exp2f(fmaf(d, -LOG2E, LOG2E));
                bool same = (a >> 2) == (b >> 2);
                accS[rr] += same ? 0.f : e;
                if (same && a < b) {
                    int i = a & 3, j = b & 3;
                    int idx = i * (7 - i) / 2 + (j - i - 1);
                    int cls = (rbase + a) >> 2;
                    posD[cls * 6 + idx] = d;
                }
            }
        }
    }
    // reduce over the 16 col-lanes (lr varies within xor masks 1..8)
    #pragma unroll
    for (int rr = 0; rr < 4; ++rr) {
        #pragma unroll
        for (int m = 1; m < 16; m <<= 1) accS[rr] += __shfl_xor(accS[rr], m, 64);
    }
    if (lr == 0) {
        #pragma unroll
        for (int rr = 0; rr < 4; ++rr)
            partial[cs * NROWS + rbase + lg * 4 + rr] = f2bf(accS[rr]);
    }
}

// single block: S = sum of 16 bf16 split panels, J per pair, relu^2, mean
__global__ void tail_kernel(const unsigned short* __restrict__ partial,
                            const float* __restrict__ posD,
                            float* __restrict__ out) {
    const int c = threadIdx.x;    // class 0..1023
    float S[4] = {0.f, 0.f, 0.f, 0.f};
    #pragma unroll
    for (int sp = 0; sp < NSPLIT; ++sp) {
        ushort4 v = *reinterpret_cast<const ushort4*>(partial + sp * NROWS + 4 * c);
        S[0] += bf2f(v.x); S[1] += bf2f(v.y); S[2] += bf2f(v.z); S[3] += bf2f(v.w);
    }
    const int II[6] = {0, 0, 0, 1, 1, 2};
    const int JJ[6] = {1, 2, 3, 2, 3, 3};
    float acc = 0.f;
    #pragma unroll
    for (int p = 0; p < 6; ++p) {
        float d = posD[c * 6 + p];
        float J = __logf(S[II[p]] + S[JJ[p]]) + d;
        float r = fmaxf(J, 0.f);
        acc += r * r;
    }
    // block reduce 1024 -> 1
    #pragma unroll
    for (int m = 1; m < 64; m <<= 1) acc += __shfl_xor(acc, m, 64);
    __shared__ float red[16];
    if ((c & 63) == 0) red[c >> 6] = acc;
    __syncthreads();
    if (c < 64) {
        float v = (c < 16) ? red[c] : 0.f;
        #pragma unroll
        for (int m = 1; m < 16; m <<= 1) v += __shfl_xor(v, m, 64);
        if (c == 0) out[0] = v * (1.0f / (2.0f * (float)NPAIR));
    }
}

extern "C" void kernel_launch(void* const* d_in, const int* in_sizes, int n_in,
                              void* d_out, int out_size, void* d_ws, size_t ws_size,
                              hipStream_t stream) {
    const float* x = (const float*)d_in[0];
    char* ws = (char*)d_ws;
    unsigned short* xbf = (unsigned short*)ws;                        // 1 MB
    float* norms = (float*)(ws + 1048576);                            // 16 KB
    unsigned short* partial = (unsigned short*)(ws + 1048576 + 16384);// 16*4096 bf16 = 128 KB
    float* posD = (float*)(ws + 1048576 + 16384 + 131072);            // 24 KB
    float* out = (float*)d_out;

    hipLaunchKernelGGL(prep_kernel, dim3(NROWS / 4), dim3(256), 0, stream, x, xbf, norms);
    hipLaunchKernelGGL(main_kernel, dim3(512), dim3(512), 0, stream, xbf, norms, partial, posD);
    hipLaunchKernelGGL(tail_kernel, dim3(1), dim3(1024), 0, stream, partial, posD, out);
}

// Round 10
// 23.332 us; speedup vs baseline: 1.4147x; 1.0215x over previous
//
#include <hip/hip_runtime.h>

#define NROWS 4096
#define DIM 128
#define PCLS 1024
#define NPAIR 6144
#define MARGIN 1.0f
#define EPS 1e-6f
#define LOG2E 1.4426950408889634f
#define NSPLIT 16

typedef __attribute__((ext_vector_type(8))) short bf16x8;
typedef __attribute__((ext_vector_type(4))) float f32x4;

union FragU { uint4 u; bf16x8 v; unsigned short us[8]; };

__device__ __forceinline__ unsigned short f2bf(float f) {
    unsigned int b = __float_as_uint(f);
    b = (b + 0x7FFFu + ((b >> 16) & 1u)) >> 16;
    return (unsigned short)b;
}
__device__ __forceinline__ float bf2f(unsigned short u) {
    return __uint_as_float((unsigned int)u << 16);
}

// Fused prep+main: f32 -> bf16 conversion, norms (f32-exact, folded into the
// A-frag loads and B-staging loop at zero extra global reads), Gram tiles via
// bf16 MFMA, exp epilogue, positive-pair extraction.
// grid: 32 row-blocks (128 rows) x 16 col-splits (256 cols) = 512 blocks, 512 thr.
__launch_bounds__(512, 4)
__global__ void main_kernel(const float* __restrict__ x,
                            unsigned short* __restrict__ partial,
                            float* __restrict__ posD) {
    __shared__ __align__(16) unsigned short lds[256 * DIM]; // 64 KB bf16 B-panel
    __shared__ float normRow[128];
    __shared__ float normCol[256];
    const int t = threadIdx.x;
    const int w = t >> 6;
    const int l = t & 63;
    const int rb = blockIdx.x >> 4;
    const int cs = blockIdx.x & 15;
    const int rbase = rb * 128 + w * 16;   // this wave's 16 rows
    const int cbase = cs * 256;
    const int lg = l >> 4;                 // k-group (0..3)
    const int lr = l & 15;                 // frag row/col index

    // ---- A fragments (16 rows x 128 k): f32 load + convert; row norms fused.
    // lane (lg,lr) holds row rbase+lr, k in [s*32+lg*8, +8)
    FragU afr[4];
    float rn = 0.f;
    const float* arow = x + (size_t)(rbase + lr) * DIM + lg * 8;
    #pragma unroll
    for (int s = 0; s < 4; ++s) {
        float4 a0 = *reinterpret_cast<const float4*>(arow + s * 32);
        float4 a1 = *reinterpret_cast<const float4*>(arow + s * 32 + 4);
        afr[s].us[0] = f2bf(a0.x); afr[s].us[1] = f2bf(a0.y);
        afr[s].us[2] = f2bf(a0.z); afr[s].us[3] = f2bf(a0.w);
        afr[s].us[4] = f2bf(a1.x); afr[s].us[5] = f2bf(a1.y);
        afr[s].us[6] = f2bf(a1.z); afr[s].us[7] = f2bf(a1.w);
        rn = fmaf(a0.x, a0.x, rn); rn = fmaf(a0.y, a0.y, rn);
        rn = fmaf(a0.z, a0.z, rn); rn = fmaf(a0.w, a0.w, rn);
        rn = fmaf(a1.x, a1.x, rn); rn = fmaf(a1.y, a1.y, rn);
        rn = fmaf(a1.z, a1.z, rn); rn = fmaf(a1.w, a1.w, rn);
    }
    rn += __shfl_xor(rn, 16, 64);          // reduce across lg
    rn += __shfl_xor(rn, 32, 64);
    if (lg == 0) normRow[w * 16 + lr] = rn;

    // ---- B-panel staging (256 cols x 128 k) f32 -> bf16, XOR-swizzled,
    //      col norms fused (each 16-lane group stages one full column/iter)
    #pragma unroll
    for (int q = 0; q < 8; ++q) {
        int col = q * 32 + (t >> 4);       // 0..255, each col once overall
        int if32 = (t & 15) * 8;           // f32 offset within column
        const float* bp = x + (size_t)(cbase + col) * DIM + if32;
        float4 b0 = *reinterpret_cast<const float4*>(bp);
        float4 b1 = *reinterpret_cast<const float4*>(bp + 4);
        FragU h;
        h.us[0] = f2bf(b0.x); h.us[1] = f2bf(b0.y);
        h.us[2] = f2bf(b0.z); h.us[3] = f2bf(b0.w);
        h.us[4] = f2bf(b1.x); h.us[5] = f2bf(b1.y);
        h.us[6] = f2bf(b1.z); h.us[7] = f2bf(b1.w);
        int ib = if32 * 2;                 // byte offset, multiple of 16
        *reinterpret_cast<uint4*>(
            (char*)lds + col * 256 + (ib ^ ((col & 7) << 4))) = h.u;
        float cn = 0.f;
        cn = fmaf(b0.x, b0.x, cn); cn = fmaf(b0.y, b0.y, cn);
        cn = fmaf(b0.z, b0.z, cn); cn = fmaf(b0.w, b0.w, cn);
        cn = fmaf(b1.x, b1.x, cn); cn = fmaf(b1.y, b1.y, cn);
        cn = fmaf(b1.z, b1.z, cn); cn = fmaf(b1.w, b1.w, cn);
        cn += __shfl_xor(cn, 1, 64);
        cn += __shfl_xor(cn, 2, 64);
        cn += __shfl_xor(cn, 4, 64);
        cn += __shfl_xor(cn, 8, 64);
        if ((t & 15) == 0) normCol[col] = cn;
    }

    __syncthreads();

    // per-lane norms from LDS (njv: same addr across lg -> broadcast)
    float njv[16];
    #pragma unroll
    for (int tile = 0; tile < 16; ++tile)
        njv[tile] = normCol[tile * 16 + lr];
    float ni[4];
    #pragma unroll
    for (int rr = 0; rr < 4; ++rr)
        ni[rr] = normRow[w * 16 + lg * 4 + rr] + EPS;  // fold +EPS

    float accS[4] = {0.f, 0.f, 0.f, 0.f};

    #pragma unroll
    for (int tile = 0; tile < 16; ++tile) {
        const int lcol = tile * 16 + lr;
        const float nj = njv[tile];
        const char* bbase = (const char*)lds + lcol * 256;
        const int xr = (lcol & 7) << 4;
        f32x4 acc = {0.f, 0.f, 0.f, 0.f};
        #pragma unroll
        for (int s = 0; s < 4; ++s) {
            FragU bu;
            int inner = s * 64 + lg * 16;
            bu.u = *reinterpret_cast<const uint4*>(bbase + (inner ^ xr));
            acc = __builtin_amdgcn_mfma_f32_16x16x32_bf16(afr[s].v, bu.v, acc, 0, 0, 0);
        }
        const bool diag = (cbase + tile * 16) == rbase;  // wave-uniform
        if (!diag) {
            #pragma unroll
            for (int rr = 0; rr < 4; ++rr) {
                float nn = ni[rr] + nj;
                float d2 = fmaf(-2.0f, acc[rr], nn);
                float d = __builtin_amdgcn_sqrtf(fmaxf(d2, EPS));
                accS[rr] += __builtin_amdgcn_exp2f(fmaf(d, -LOG2E, LOG2E));
            }
        } else {
            // diagonal 16x16 tile: same-class masking + positive-pair extraction
            #pragma unroll
            for (int rr = 0; rr < 4; ++rr) {
                int a = lg * 4 + rr;               // local row 0..15
                int b = lr;                        // local col 0..15
                float nn = ni[rr] + nj;
                float d2 = fmaf(-2.0f, acc[rr], nn);
                float d = __builtin_amdgcn_sqrtf(fmaxf(d2, EPS));
                float e = __builtin_amdgcn_exp2f(fmaf(d, -LOG2E, LOG2E));
                bool same = (a >> 2) == (b >> 2);
                accS[rr] += same ? 0.f : e;
                if (same && a < b) {
                    int i = a & 3, j = b & 3;
                    int idx = i * (7 - i) / 2 + (j - i - 1);
                    int cls = (rbase + a) >> 2;
                    posD[cls * 6 + idx] = d;
                }
            }
        }
    }
    // reduce over the 16 col-lanes
    #pragma unroll
    for (int rr = 0; rr < 4; ++rr) {
        #pragma unroll
        for (int m = 1; m < 16; m <<= 1) accS[rr] += __shfl_xor(accS[rr], m, 64);
    }
    if (lr == 0) {
        #pragma unroll
        for (int rr = 0; rr < 4; ++rr)
            partial[cs * NROWS + rbase + lg * 4 + rr] = f2bf(accS[rr]);
    }
}

// single block: S = sum of 16 bf16 split panels, J per pair, relu^2, mean
__global__ void tail_kernel(const unsigned short* __restrict__ partial,
                            const float* __restrict__ posD,
                            float* __restrict__ out) {
    const int c = threadIdx.x;    // class 0..1023
    float S[4] = {0.f, 0.f, 0.f, 0.f};
    #pragma unroll
    for (int sp = 0; sp < NSPLIT; ++sp) {
        ushort4 v = *reinterpret_cast<const ushort4*>(partial + sp * NROWS + 4 * c);
        S[0] += bf2f(v.x); S[1] += bf2f(v.y); S[2] += bf2f(v.z); S[3] += bf2f(v.w);
    }
    const int II[6] = {0, 0, 0, 1, 1, 2};
    const int JJ[6] = {1, 2, 3, 2, 3, 3};
    float acc = 0.f;
    #pragma unroll
    for (int p = 0; p < 6; ++p) {
        float d = posD[c * 6 + p];
        float J = __logf(S[II[p]] + S[JJ[p]]) + d;
        float r = fmaxf(J, 0.f);
        acc += r * r;
    }
    // block reduce 1024 -> 1
    #pragma unroll
    for (int m = 1; m < 64; m <<= 1) acc += __shfl_xor(acc, m, 64);
    __shared__ float red[16];
    if ((c & 63) == 0) red[c >> 6] = acc;
    __syncthreads();
    if (c < 64) {
        float v = (c < 16) ? red[c] : 0.f;
        #pragma unroll
        for (int m = 1; m < 16; m <<= 1) v += __shfl_xor(v, m, 64);
        if (c == 0) out[0] = v * (1.0f / (2.0f * (float)NPAIR));
    }
}

extern "C" void kernel_launch(void* const* d_in, const int* in_sizes, int n_in,
                              void* d_out, int out_size, void* d_ws, size_t ws_size,
                              hipStream_t stream) {
    const float* x = (const float*)d_in[0];
    char* ws = (char*)d_ws;
    unsigned short* partial = (unsigned short*)ws;        // 16*4096 bf16 = 128 KB
    float* posD = (float*)(ws + 131072);                  // 24 KB
    float* out = (float*)d_out;

    hipLaunchKernelGGL(main_kernel, dim3(512), dim3(512), 0, stream, x, partial, posD);
    hipLaunchKernelGGL(tail_kernel, dim3(1), dim3(1024), 0, stream, partial, posD, out);
}